// Round 17
// baseline (5772.203 us; speedup 1.0000x reference)
//
#include <hip/hip_runtime.h>
#include <hip/hip_bf16.h>

typedef unsigned short u16;
typedef unsigned int   u32;
typedef __attribute__((ext_vector_type(8))) short s16x8;   // 8 bf16 = 4 VGPRs
typedef __attribute__((ext_vector_type(4))) float f32x4;

// ---- problem constants ----
#define NB   1024
#define TT   64
#define DXL  300
#define DXA  74
#define DXV  35
#define DX   (DXL+DXA+DXV)   // 409
#define DHL  512
#define DHA  256
#define DHV  256
#define TOTH 1024
#define MEMD 512
#define HMLP 1024
#define ATTIN 2048
#define GAMIN 2560
// padded x widths (multiples of 64)
#define PXL  320
#define PXA  128
#define PXV  64

__device__ __forceinline__ u16 f2b(float f) {
    union { float f; u32 u; } x; x.f = f;
    u32 r = x.u + 0x7fffu + ((x.u >> 16) & 1u);
    return (u16)(r >> 16);
}

__device__ __forceinline__ void gload_lds16(const void* g, void* l) {
    __builtin_amdgcn_global_load_lds(
        (const __attribute__((address_space(1))) unsigned int*)g,
        (__attribute__((address_space(3))) unsigned int*)l,
        16, 0, 0);
}

// shared problem descriptor. mkgp stores Nout in `nout`; launchers derive gx.
struct GP {
    const u16* A0; const u16* A1; const u16* W0; const u16* W1;
    const float* b0; const float* b1; void* C;
    int lda0, K0, lda1, K1, ldw0, ldw1, ldc, act, outbf, bStart, gx, nout;
};

// ---------------------------------------------------------------------------
// 64x64-tile grouped GEMM (R10 body, best-measured). Used for G2 + prologue.
// ---------------------------------------------------------------------------
__global__ __launch_bounds__(256) void gemm_group64(GP p0, GP p1, GP p2,
                                                    GP p3, GP p4, GP p5)
{
    __shared__ u16 As[2][64 * 64];
    __shared__ u16 Bs[2][64 * 64];
    GP p;
    {
        int bx = blockIdx.x;
        if      (bx >= p5.bStart) p = p5;
        else if (bx >= p4.bStart) p = p4;
        else if (bx >= p3.bStart) p = p3;
        else if (bx >= p2.bStart) p = p2;
        else if (bx >= p1.bStart) p = p1;
        else                      p = p0;
    }
    const int tid  = threadIdx.x;
    const int wid  = tid >> 6;
    const int lane = tid & 63;
    const int local = blockIdx.x - p.bStart;
    const int by  = local / p.gx;            // 0..15
    const int bm  = by * 64;
    const int bn  = (local - by * p.gx) * 64;
    const int wr = wid >> 1, wc = wid & 1;
    const int nt = (p.K0 + p.K1) >> 6;
    const int e0 = wid * 2 * 64 + lane;

    auto stage = [&](int t, int buf) {
        int k0 = t << 6;
        const u16 *Ap, *Wp; int ldA, ldW, ka;
        if (k0 < p.K0) { Ap = p.A0; ldA = p.lda0; ka = k0;        Wp = p.W0; ldW = p.ldw0; }
        else           { Ap = p.A1; ldA = p.lda1; ka = k0 - p.K0; Wp = p.W1; ldW = p.ldw1; }
        #pragma unroll
        for (int i = 0; i < 2; ++i) {
            int e   = e0 + i * 64;
            int row = e >> 3;
            int c   = (e & 7) ^ (row & 7);
            gload_lds16(Ap + (size_t)(bm + row) * ldA + ka + c * 8,
                        (char*)&As[buf][0] + (wid * 2 + i) * 1024);
            gload_lds16(Wp + (size_t)(bn + row) * ldW + ka + c * 8,
                        (char*)&Bs[buf][0] + (wid * 2 + i) * 1024);
        }
    };

    f32x4 acc[2][2] = {};
    stage(0, 0);
    __syncthreads();

    for (int t = 0; t < nt; ++t) {
        if (t + 1 < nt) stage(t + 1, (t + 1) & 1);
        const char* Ab = (const char*)&As[t & 1][0];
        const char* Bb = (const char*)&Bs[t & 1][0];
        #pragma unroll
        for (int ks = 0; ks < 2; ++ks) {
            s16x8 af[2], bf[2];
            const int ca = ks * 4 + (lane >> 4);
            #pragma unroll
            for (int f = 0; f < 2; ++f) {
                int ra = wr * 32 + f * 16 + (lane & 15);
                af[f] = *(const s16x8*)(Ab + ra * 128 + ((ca ^ (ra & 7))) * 16);
                int rb = wc * 32 + f * 16 + (lane & 15);
                bf[f] = *(const s16x8*)(Bb + rb * 128 + ((ca ^ (rb & 7))) * 16);
            }
            #pragma unroll
            for (int fi = 0; fi < 2; ++fi)
                #pragma unroll
                for (int fj = 0; fj < 2; ++fj)
                    acc[fi][fj] = __builtin_amdgcn_mfma_f32_16x16x32_bf16(
                        af[fi], bf[fj], acc[fi][fj], 0, 0, 0);
        }
        __syncthreads();
    }

    #pragma unroll
    for (int fi = 0; fi < 2; ++fi)
        #pragma unroll
        for (int fj = 0; fj < 2; ++fj) {
            int col = bn + wc * 32 + fj * 16 + (lane & 15);
            float bia = p.b0[col];
            if (p.b1) bia += p.b1[col];
            #pragma unroll
            for (int r4 = 0; r4 < 4; ++r4) {
                int row = bm + wr * 32 + fi * 16 + (lane >> 4) * 4 + r4;
                float v = acc[fi][fj][r4] + bia;
                if (p.act == 1)      v = fmaxf(v, 0.f);
                else if (p.act == 2) v = 1.f / (1.f + __expf(-v));
                else if (p.act == 3) v = tanhf(v);
                if (p.outbf) ((u16*)p.C)[(size_t)row * p.ldc + col] = f2b(v);
                else         ((float*)p.C)[(size_t)row * p.ldc + col] = v;
            }
        }
}

// ---------------------------------------------------------------------------
// 128x128-tile grouped GEMM (R5-proven body + 1-D problem-major decode).
// Used for G1: halves staged operand traffic per FLOP (the one un-confounded
// lever left; R11/R13/R14/R15 falsified BW-path, barrier, latency, HBM-dup).
// 512 blocks = 2/CU; dispatch order pairs long(nt=40) with short lstm blocks.
// ---------------------------------------------------------------------------
__global__ __launch_bounds__(256) void gemm_group128(GP p0, GP p1, GP p2,
                                                     GP p3, GP p4, GP p5)
{
    __shared__ u16 As[2][128 * 64];
    __shared__ u16 Bs[2][128 * 64];
    GP p;
    {
        int bx = blockIdx.x;
        if      (bx >= p5.bStart) p = p5;
        else if (bx >= p4.bStart) p = p4;
        else if (bx >= p3.bStart) p = p3;
        else if (bx >= p2.bStart) p = p2;
        else if (bx >= p1.bStart) p = p1;
        else                      p = p0;
    }
    const int tid  = threadIdx.x;
    const int wid  = tid >> 6;
    const int lane = tid & 63;
    const int local = blockIdx.x - p.bStart;
    const int by  = local / p.gx;            // 0..7
    const int bm  = by * 128;
    const int bn  = (local - by * p.gx) * 128;
    const int wr = wid >> 1, wc = wid & 1;
    const int nt = (p.K0 + p.K1) >> 6;

    auto stage = [&](int t, int buf) {
        int k0 = t << 6;
        const u16 *Ap, *Wp; int ldA, ldW, ka;
        if (k0 < p.K0) { Ap = p.A0; ldA = p.lda0; ka = k0;        Wp = p.W0; ldW = p.ldw0; }
        else           { Ap = p.A1; ldA = p.lda1; ka = k0 - p.K0; Wp = p.W1; ldW = p.ldw1; }
        #pragma unroll
        for (int i = 0; i < 4; ++i) {
            int e   = tid + 256 * i;          // 0..1023
            int row = e >> 3;                 // 0..127
            int c   = (e & 7) ^ (row & 7);
            char* dA = (char*)&As[buf][0] + wid * 1024 + i * 4096;
            char* dB = (char*)&Bs[buf][0] + wid * 1024 + i * 4096;
            gload_lds16(Ap + (size_t)(bm + row) * ldA + ka + c * 8, dA);
            gload_lds16(Wp + (size_t)(bn + row) * ldW + ka + c * 8, dB);
        }
    };

    f32x4 acc[4][4] = {};
    stage(0, 0);
    __syncthreads();

    for (int t = 0; t < nt; ++t) {
        if (t + 1 < nt) stage(t + 1, (t + 1) & 1);
        const char* Ab = (const char*)&As[t & 1][0];
        const char* Bb = (const char*)&Bs[t & 1][0];
        #pragma unroll
        for (int ks = 0; ks < 2; ++ks) {
            s16x8 af[4], bf[4];
            const int ca = ks * 4 + (lane >> 4);
            #pragma unroll
            for (int m = 0; m < 4; ++m) {
                int ra = wr * 64 + m * 16 + (lane & 15);
                af[m] = *(const s16x8*)(Ab + ra * 128 + ((ca ^ (ra & 7))) * 16);
            }
            #pragma unroll
            for (int n = 0; n < 4; ++n) {
                int rb = wc * 64 + n * 16 + (lane & 15);
                bf[n] = *(const s16x8*)(Bb + rb * 128 + ((ca ^ (rb & 7))) * 16);
            }
            #pragma unroll
            for (int m = 0; m < 4; ++m)
                #pragma unroll
                for (int n = 0; n < 4; ++n)
                    acc[m][n] = __builtin_amdgcn_mfma_f32_16x16x32_bf16(
                        af[m], bf[n], acc[m][n], 0, 0, 0);
        }
        __syncthreads();
    }

    #pragma unroll
    for (int m = 0; m < 4; ++m)
        #pragma unroll
        for (int n = 0; n < 4; ++n) {
            int col = bn + wc * 64 + n * 16 + (lane & 15);
            float bia = p.b0[col];
            if (p.b1) bia += p.b1[col];
            #pragma unroll
            for (int r4 = 0; r4 < 4; ++r4) {
                int row = bm + wr * 64 + m * 16 + (lane >> 4) * 4 + r4;
                float v = acc[m][n][r4] + bia;
                if (p.act == 1)      v = fmaxf(v, 0.f);
                else if (p.act == 2) v = 1.f / (1.f + __expf(-v));
                else if (p.act == 3) v = tanhf(v);
                if (p.outbf) ((u16*)p.C)[(size_t)row * p.ldc + col] = f2b(v);
                else         ((float*)p.C)[(size_t)row * p.ldc + col] = v;
            }
        }
}

// ---------------------------------------------------------------------------
// pointwise device helpers
// ---------------------------------------------------------------------------
__device__ __forceinline__ void lstm_elem(
    const float* __restrict__ gl, const float* __restrict__ ga,
    const float* __restrict__ gv, const float* __restrict__ cs_prev,
    float* __restrict__ cs_new, u16* __restrict__ cs_new_b,
    u16* __restrict__ hs_new_b, int idx)
{
    int n = idx >> 10, u = idx & 1023;
    const float* g; int dh, gu;
    if (u < DHL)            { g = gl; dh = DHL; gu = u; }
    else if (u < DHL + DHA) { g = ga; dh = DHA; gu = u - DHL; }
    else                    { g = gv; dh = DHV; gu = u - DHL - DHA; }
    const float* grow = g + (size_t)n * 4 * dh;
    float gi = grow[gu], gf = grow[dh + gu], gg = grow[2 * dh + gu], go = grow[3 * dh + gu];
    float c  = cs_prev[idx];
    float si = 1.f / (1.f + __expf(-gi));
    float sf = 1.f / (1.f + __expf(-gf));
    float so = 1.f / (1.f + __expf(-go));
    float c2 = sf * c + si * tanhf(gg);
    float h2 = so * tanhf(c2);
    cs_new[idx]   = c2;
    cs_new_b[idx] = f2b(c2);
    hs_new_b[idx] = f2b(h2);
}

__device__ __forceinline__ void xcvt_elem(
    const float* __restrict__ X, int t, int n, int u,
    u16* __restrict__ xl, u16* __restrict__ xa, u16* __restrict__ xv)
{
    const float* row = X + ((size_t)t * NB + n) * DX;
    if (u < PXL)            xl[n * PXL + u] = f2b(u < DXL ? row[u] : 0.f);
    else if (u < PXL + PXA) { int q = u - PXL;       xa[n * PXA + q] = f2b(q < DXA ? row[DXL + q] : 0.f); }
    else                    { int q = u - PXL - PXA; xv[n * PXV + q] = f2b(q < DXV ? row[DXL + DXA + q] : 0.f); }
}

__global__ void lstm_pointwise(const float* __restrict__ gl,
                               const float* __restrict__ ga,
                               const float* __restrict__ gv,
                               const float* __restrict__ cs_prev,
                               float* __restrict__ cs_new,
                               u16* __restrict__ cs_new_b,
                               u16* __restrict__ hs_new_b,
                               const float* __restrict__ X, int tnext,
                               u16* __restrict__ xl, u16* __restrict__ xa,
                               u16* __restrict__ xv)
{
    int idx = blockIdx.x * blockDim.x + threadIdx.x;
    if (idx >= NB * TOTH) return;
    lstm_elem(gl, ga, gv, cs_prev, cs_new, cs_new_b, hs_new_b, idx);
    int n = idx >> 10, u = idx & 1023;
    if (tnext < TT && u < 512) xcvt_elem(X, tnext, n, u, xl, xa, xv);
}

__global__ __launch_bounds__(256) void fused_mid(
    const float* __restrict__ logits,
    const float* __restrict__ csP,
    const float* __restrict__ csN,
    u16* __restrict__ attended_b,
    int do_mem,
    float* __restrict__ memb, u16* __restrict__ membb,
    const float* __restrict__ g1, const float* __restrict__ g2,
    const float* __restrict__ chat,
    int do_pw,
    const float* __restrict__ gl, const float* __restrict__ ga,
    const float* __restrict__ gv,
    float* __restrict__ pw_cs_new,
    u16* __restrict__ pw_cs_new_b,
    u16* __restrict__ pw_hs_new_b,
    const float* __restrict__ X, int tnext,
    u16* __restrict__ xl, u16* __restrict__ xa, u16* __restrict__ xv)
{
    int n = blockIdx.x;
    int tid = threadIdx.x, lane = tid & 63, wid = tid >> 6;

    if (do_mem) {
        for (int k = tid; k < MEMD; k += 256) {
            size_t i = (size_t)n * MEMD + k;
            float v = g1[i] * memb[i] + g2[i] * chat[i];
            memb[i]  = v;
            membb[i] = f2b(v);
        }
    }

    const float* z = logits + (size_t)n * ATTIN;
    __shared__ float sred[4];

    float m = -1e30f;
    for (int k = tid; k < ATTIN; k += 256) m = fmaxf(m, z[k]);
    #pragma unroll
    for (int off = 1; off < 64; off <<= 1) m = fmaxf(m, __shfl_xor(m, off));
    if (lane == 0) sred[wid] = m;
    __syncthreads();
    m = fmaxf(fmaxf(sred[0], sred[1]), fmaxf(sred[2], sred[3]));
    __syncthreads();

    float s = 0.f;
    for (int k = tid; k < ATTIN; k += 256) s += __expf(z[k] - m);
    #pragma unroll
    for (int off = 1; off < 64; off <<= 1) s += __shfl_xor(s, off);
    if (lane == 0) sred[wid] = s;
    __syncthreads();
    s = sred[0] + sred[1] + sred[2] + sred[3];
    float inv = 1.f / s;

    for (int k = tid; k < ATTIN; k += 256) {
        float cs = (k < TOTH) ? csP[(size_t)n * TOTH + k]
                              : csN[(size_t)n * TOTH + (k - TOTH)];
        attended_b[(size_t)n * ATTIN + k] = f2b(__expf(z[k] - m) * inv * cs);
    }

    if (do_pw) {
        __syncthreads();
        #pragma unroll
        for (int j = 0; j < 4; ++j) {
            int u = tid + j * 256;
            lstm_elem(gl, ga, gv, csN, pw_cs_new, pw_cs_new_b, pw_hs_new_b,
                      n * 1024 + u);
        }
        if (tnext < TT) {
            #pragma unroll
            for (int j = 0; j < 2; ++j) {
                int u = tid + j * 256;
                xcvt_elem(X, tnext, n, u, xl, xa, xv);
            }
        }
    }
}

__global__ void mem_update(float* __restrict__ memb,
                           u16* __restrict__ memb_b,
                           const float* __restrict__ g1,
                           const float* __restrict__ g2,
                           const float* __restrict__ chat)
{
    int idx = blockIdx.x * blockDim.x + threadIdx.x;
    if (idx >= NB * MEMD) return;
    float v = g1[idx] * memb[idx] + g2[idx] * chat[idx];
    memb[idx]   = v;
    memb_b[idx] = f2b(v);
}

__global__ __launch_bounds__(256) void out_dot(const float* __restrict__ hid,
                                               const float* __restrict__ w2,
                                               const float* __restrict__ b2,
                                               float* __restrict__ out)
{
    int wid = threadIdx.x >> 6, lane = threadIdx.x & 63;
    int n = blockIdx.x * 4 + wid;
    if (n >= NB) return;
    const float* h = hid + (size_t)n * HMLP;
    float s = 0.f;
    for (int k = lane; k < HMLP; k += 64) s += h[k] * w2[k];
    #pragma unroll
    for (int off = 1; off < 64; off <<= 1) s += __shfl_xor(s, off);
    if (lane == 0) out[n] = s + b2[0];
}

__global__ void cvt_x(const float* __restrict__ X,
                      u16* __restrict__ xl, u16* __restrict__ xa, u16* __restrict__ xv,
                      int t)
{
    int idx = blockIdx.x * blockDim.x + threadIdx.x;
    if (idx >= NB * 512) return;
    xcvt_elem(X, t, idx >> 9, idx & 511, xl, xa, xv);
}

__global__ void concat2(const float* __restrict__ a, const float* __restrict__ b,
                        float* __restrict__ d)
{
    int i = blockIdx.x * 256 + threadIdx.x;
    if (i < 1024)      d[i] = a[i];
    else if (i < 2048) d[i] = b[i - 1024];
}

#define NWC 15
struct WDesc { const float* src; u16* dst; int rows, ksrc, kdst, bstart; };
struct WPack { WDesc d[NWC]; };

__global__ __launch_bounds__(256) void wcvt_all(WPack wp)
{
    int bx = blockIdx.x;
    int di = 0;
    #pragma unroll
    for (int i = 1; i < NWC; ++i) if (bx >= wp.d[i].bstart) di = i;
    WDesc d = wp.d[di];
    int n = d.rows * d.kdst;
    int base = (bx - d.bstart) * 2048 + threadIdx.x;
    if (d.ksrc == d.kdst) {
        #pragma unroll
        for (int j = 0; j < 8; ++j) {
            int idx = base + j * 256;
            if (idx < n) d.dst[idx] = f2b(d.src[idx]);
        }
    } else {
        #pragma unroll
        for (int j = 0; j < 8; ++j) {
            int idx = base + j * 256;
            if (idx < n) {
                int r = idx / d.kdst, c = idx - r * d.kdst;
                d.dst[idx] = f2b(c < d.ksrc ? d.src[(size_t)r * d.ksrc + c] : 0.f);
            }
        }
    }
}

__global__ void fill0(u32* __restrict__ p, int n)
{
    int i = blockIdx.x * blockDim.x + threadIdx.x;
    if (i < n) p[i] = 0u;
}

// ---------------------------------------------------------------------------
// host side
// ---------------------------------------------------------------------------
static GP mkgp(const u16* A0, int lda0, int K0, const u16* A1, int lda1, int K1,
               const u16* W0, int ldw0, const u16* W1, int ldw1,
               const float* b0, const float* b1, void* C, int ldc,
               int Nout, int act, int outbf)
{
    GP p;
    p.A0 = A0; p.A1 = A1; p.W0 = W0; p.W1 = W1; p.b0 = b0; p.b1 = b1; p.C = C;
    p.lda0 = lda0; p.K0 = K0; p.lda1 = lda1; p.K1 = K1;
    p.ldw0 = ldw0; p.ldw1 = ldw1; p.ldc = ldc; p.act = act; p.outbf = outbf;
    p.bStart = 0; p.gx = 0; p.nout = Nout;
    return p;
}

static void launch_group64(hipStream_t s, GP* p, int np)
{
    int total = 0;
    for (int i = 0; i < np; ++i) {
        p[i].gx = p[i].nout / 64;
        p[i].bStart = total;
        total += p[i].gx * 16;
    }
    GP dummy = {};
    dummy.bStart = 0x7fffffff;
    GP a1 = (np > 1) ? p[1] : dummy;
    GP a2 = (np > 2) ? p[2] : dummy;
    GP a3 = (np > 3) ? p[3] : dummy;
    GP a4 = (np > 4) ? p[4] : dummy;
    GP a5 = (np > 5) ? p[5] : dummy;
    gemm_group64<<<dim3(total), 256, 0, s>>>(p[0], a1, a2, a3, a4, a5);
}

static void launch_group128(hipStream_t s, GP* p, int np)
{
    int total = 0;
    for (int i = 0; i < np; ++i) {
        p[i].gx = p[i].nout / 128;
        p[i].bStart = total;
        total += p[i].gx * 8;
    }
    GP dummy = {};
    dummy.bStart = 0x7fffffff;
    GP a1 = (np > 1) ? p[1] : dummy;
    GP a2 = (np > 2) ? p[2] : dummy;
    GP a3 = (np > 3) ? p[3] : dummy;
    GP a4 = (np > 4) ? p[4] : dummy;
    GP a5 = (np > 5) ? p[5] : dummy;
    gemm_group128<<<dim3(total), 256, 0, s>>>(p[0], a1, a2, a3, a4, a5);
}

extern "C" void kernel_launch(void* const* d_in, const int* in_sizes, int n_in,
                              void* d_out, int out_size, void* d_ws, size_t ws_size,
                              hipStream_t stream)
{
    const float* X     = (const float*)d_in[0];
    const float* Wih_l = (const float*)d_in[5];
    const float* Whh_l = (const float*)d_in[6];
    const float* bih_l = (const float*)d_in[7];
    const float* bhh_l = (const float*)d_in[8];
    const float* Wih_a = (const float*)d_in[9];
    const float* Whh_a = (const float*)d_in[10];
    const float* bih_a = (const float*)d_in[11];
    const float* bhh_a = (const float*)d_in[12];
    const float* Wih_v = (const float*)d_in[13];
    const float* Whh_v = (const float*)d_in[14];
    const float* bih_v = (const float*)d_in[15];
    const float* bhh_v = (const float*)d_in[16];
    const float* a1w1  = (const float*)d_in[17];
    const float* a1b1  = (const float*)d_in[18];
    const float* a1w2  = (const float*)d_in[19];
    const float* a1b2  = (const float*)d_in[20];
    const float* a2w1  = (const float*)d_in[21];
    const float* a2b1  = (const float*)d_in[22];
    const float* a2w2  = (const float*)d_in[23];
    const float* a2b2  = (const float*)d_in[24];
    const float* g1w1  = (const float*)d_in[25];
    const float* g1b1  = (const float*)d_in[26];
    const float* g1w2  = (const float*)d_in[27];
    const float* g1b2  = (const float*)d_in[28];
    const float* g2w1  = (const float*)d_in[29];
    const float* g2b1  = (const float*)d_in[30];
    const float* g2w2  = (const float*)d_in[31];
    const float* g2b2  = (const float*)d_in[32];
    const float* ow1   = (const float*)d_in[33];
    const float* ob1   = (const float*)d_in[34];
    const float* ow2   = (const float*)d_in[35];
    const float* ob2   = (const float*)d_in[36];
    float* out = (float*)d_out;

    // ---- workspace carve (256B aligned) ----
    char* wsp = (char*)d_ws;
    auto take = [&](size_t bytes) -> char* {
        char* r = wsp; wsp += (bytes + 255) & ~(size_t)255; return r;
    };
    float* cs0  = (float*)take((size_t)NB * TOTH * 4);
    float* cs1  = (float*)take((size_t)NB * TOTH * 4);
    float* memb = (float*)take((size_t)NB * MEMD * 4);
    float* gl   = (float*)take((size_t)NB * 2048 * 4);
    float* ga   = (float*)take((size_t)NB * 1024 * 4);
    float* gv   = (float*)take((size_t)NB * 1024 * 4);
    float* lgts = (float*)take((size_t)NB * ATTIN * 4);
    float* chat = (float*)take((size_t)NB * MEMD * 4);
    float* gm1  = (float*)take((size_t)NB * MEMD * 4);
    float* gm2  = (float*)take((size_t)NB * MEMD * 4);
    float* hout = (float*)take((size_t)NB * HMLP * 4);
    float* cb2  = (float*)take((size_t)2048 * 4);
    u16* hs0b  = (u16*)take((size_t)NB * TOTH * 2);
    u16* hs1b  = (u16*)take((size_t)NB * TOTH * 2);
    u16* cs0b  = (u16*)take((size_t)NB * TOTH * 2);
    u16* cs1b  = (u16*)take((size_t)NB * TOTH * 2);
    u16* membb = (u16*)take((size_t)NB * MEMD * 2);
    u16* xlb   = (u16*)take((size_t)NB * PXL * 2);
    u16* xab   = (u16*)take((size_t)NB * PXA * 2);
    u16* xvb   = (u16*)take((size_t)NB * PXV * 2);
    u16* hid1b = (u16*)take((size_t)NB * HMLP * 2);
    u16* hcat  = (u16*)take((size_t)NB * 3072 * 2);
    u16* attdb = (u16*)take((size_t)NB * ATTIN * 2);
    u16* wihlb = (u16*)take((size_t)2048 * PXL * 2);
    u16* whhlb = (u16*)take((size_t)2048 * DHL * 2);
    u16* wihab = (u16*)take((size_t)1024 * PXA * 2);
    u16* whhab = (u16*)take((size_t)1024 * DHA * 2);
    u16* wihvb = (u16*)take((size_t)1024 * PXV * 2);
    u16* whhvb = (u16*)take((size_t)1024 * DHV * 2);
    u16* a1w1b = (u16*)take((size_t)HMLP * ATTIN * 2);
    u16* a1w2b = (u16*)take((size_t)ATTIN * HMLP * 2);
    u16* a2w1b = (u16*)take((size_t)HMLP * ATTIN * 2);
    u16* g12w1b= (u16*)take((size_t)2048 * GAMIN * 2);
    u16* a2w2b = (u16*)take((size_t)MEMD * HMLP * 2);
    u16* g1w2b = (u16*)take((size_t)MEMD * HMLP * 2);
    u16* g2w2b = (u16*)take((size_t)MEMD * HMLP * 2);
    u16* ow1b  = (u16*)take((size_t)HMLP * 1536 * 2);

    // ---- prologue ----
    {
        int nf = NB * (TOTH * 2 + MEMD);
        fill0<<<(nf + 255) / 256, 256, 0, stream>>>((u32*)cs0, nf);
        int nb = NB * (TOTH * 4 + MEMD) / 2;
        fill0<<<(nb + 255) / 256, 256, 0, stream>>>((u32*)hs0b, nb);
    }
    {
        WPack wp;
        const float* src[NWC] = { Wih_l, Whh_l, Wih_a, Whh_a, Wih_v, Whh_v,
                                  a1w1, a1w2, a2w1, g1w1, g2w1,
                                  a2w2, g1w2, g2w2, ow1 };
        u16* dst[NWC] = { wihlb, whhlb, wihab, whhab, wihvb, whhvb,
                          a1w1b, a1w2b, a2w1b, g12w1b, g12w1b + (size_t)1024 * GAMIN,
                          a2w2b, g1w2b, g2w2b, ow1b };
        int rows[NWC] = { 2048, 2048, 1024, 1024, 1024, 1024,
                          HMLP, ATTIN, HMLP, 1024, 1024,
                          MEMD, MEMD, MEMD, HMLP };
        int ksrc[NWC] = { DXL, DHL, DXA, DHA, DXV, DHV,
                          ATTIN, HMLP, ATTIN, GAMIN, GAMIN,
                          HMLP, HMLP, HMLP, 1536 };
        int kdst[NWC] = { PXL, DHL, PXA, DHA, PXV, DHV,
                          ATTIN, HMLP, ATTIN, GAMIN, GAMIN,
                          HMLP, HMLP, HMLP, 1536 };
        int total = 0;
        for (int i = 0; i < NWC; ++i) {
            wp.d[i].src = src[i]; wp.d[i].dst = dst[i];
            wp.d[i].rows = rows[i]; wp.d[i].ksrc = ksrc[i]; wp.d[i].kdst = kdst[i];
            wp.d[i].bstart = total;
            total += (rows[i] * kdst[i] + 2047) / 2048;
        }
        wcvt_all<<<total, 256, 0, stream>>>(wp);
    }
    concat2<<<8, 256, 0, stream>>>(g1b1, g2b1, cb2);
    cvt_x<<<(NB * 512 + 255) / 256, 256, 0, stream>>>(X, xlb, xab, xvb, 0);

    float* csf[2] = { cs0, cs1 };
    u16*   csb[2] = { cs0b, cs1b };
    u16*   hsb[2] = { hs0b, hs1b };

    // prologue: lstm gemms(0), pointwise(0), {att1L1(0)+lstm(1)}, att1L2(0)
    {
        GP ps[3] = {
            mkgp(xlb, PXL, PXL, hsb[0], TOTH, DHL,
                 wihlb, PXL, whhlb, DHL, bih_l, bhh_l, gl, 2048, 2048, 0, 0),
            mkgp(xab, PXA, PXA, hsb[0] + DHL, TOTH, DHA,
                 wihab, PXA, whhab, DHA, bih_a, bhh_a, ga, 1024, 1024, 0, 0),
            mkgp(xvb, PXV, PXV, hsb[0] + DHL + DHA, TOTH, DHV,
                 wihvb, PXV, whhvb, DHV, bih_v, bhh_v, gv, 1024, 1024, 0, 0) };
        launch_group64(stream, ps, 3);
    }
    lstm_pointwise<<<(NB * TOTH + 255) / 256, 256, 0, stream>>>(
        gl, ga, gv, csf[0], csf[1], csb[1], hsb[1], X, 1, xlb, xab, xvb);
    {
        GP ps[4] = {
            mkgp(csb[0], TOTH, TOTH, csb[1], TOTH, TOTH,
                 a1w1b, ATTIN, a1w1b + TOTH, ATTIN, a1b1, nullptr,
                 hid1b, HMLP, HMLP, 1, 1),
            mkgp(xlb, PXL, PXL, hsb[1], TOTH, DHL,
                 wihlb, PXL, whhlb, DHL, bih_l, bhh_l, gl, 2048, 2048, 0, 0),
            mkgp(xab, PXA, PXA, hsb[1] + DHL, TOTH, DHA,
                 wihab, PXA, whhab, DHA, bih_a, bhh_a, ga, 1024, 1024, 0, 0),
            mkgp(xvb, PXV, PXV, hsb[1] + DHL + DHA, TOTH, DHV,
                 wihvb, PXV, whhvb, DHV, bih_v, bhh_v, gv, 1024, 1024, 0, 0) };
        launch_group64(stream, ps, 4);
    }
    {
        GP ps[1] = { mkgp(hid1b, HMLP, HMLP, nullptr, 0, 0,
                          a1w2b, HMLP, nullptr, 0, a1b2, nullptr,
                          lgts, ATTIN, ATTIN, 0, 0) };
        launch_group64(stream, ps, 1);
    }

    // main loop: 3 launches/step
    for (int t = 0; t < TT; ++t) {
        // 1) fused_mid(t)
        fused_mid<<<NB, 256, 0, stream>>>(
            lgts, csf[t & 1], csf[(t + 1) & 1], attdb,
            t > 0 ? 1 : 0, memb, membb, gm1, gm2, chat,
            t < TT - 1 ? 1 : 0, gl, ga, gv,
            csf[t & 1], csb[t & 1], hsb[t & 1],
            X, t + 2, xlb, xab, xvb);

        // 2) G1 at 128x128 (halved staged traffic; 512 blocks = 2/CU;
        //    dispatch order pairs long g12 blocks with short lstm blocks)
        {
            GP ps[6]; int np = 0;
            ps[np++] = mkgp(attdb, ATTIN, ATTIN, membb, MEMD, MEMD,
                            g12w1b, GAMIN, g12w1b + ATTIN, GAMIN, cb2, nullptr,
                            hcat + 1024, 3072, 2048, 1, 1);
            ps[np++] = mkgp(attdb, ATTIN, ATTIN, nullptr, 0, 0,
                            a2w1b, ATTIN, nullptr, 0, a2b1, nullptr,
                            hcat, 3072, 1024, 1, 1);
            if (t < TT - 1)
                ps[np++] = mkgp(csb[(t + 1) & 1], TOTH, TOTH, csb[t & 1], TOTH, TOTH,
                                a1w1b, ATTIN, a1w1b + TOTH, ATTIN, a1b1, nullptr,
                                hid1b, HMLP, HMLP, 1, 1);
            if (t < TT - 2) {
                ps[np++] = mkgp(xlb, PXL, PXL, hsb[t & 1], TOTH, DHL,
                                wihlb, PXL, whhlb, DHL, bih_l, bhh_l, gl, 2048, 2048, 0, 0);
                ps[np++] = mkgp(xab, PXA, PXA, hsb[t & 1] + DHL, TOTH, DHA,
                                wihab, PXA, whhab, DHA, bih_a, bhh_a, ga, 1024, 1024, 0, 0);
                ps[np++] = mkgp(xvb, PXV, PXV, hsb[t & 1] + DHL + DHA, TOTH, DHV,
                                wihvb, PXV, whhvb, DHV, bih_v, bhh_v, gv, 1024, 1024, 0, 0);
            }
            launch_group128(stream, ps, np);
        }

        // 3) G2 at 64x64 (small-N problems would starve at 128)
        {
            GP ps[4]; int np = 0;
            if (t < TT - 1)
                ps[np++] = mkgp(hid1b, HMLP, HMLP, nullptr, 0, 0,
                                a1w2b, HMLP, nullptr, 0, a1b2, nullptr,
                                lgts, ATTIN, ATTIN, 0, 0);
            ps[np++] = mkgp(hcat, 3072, HMLP, nullptr, 0, 0,
                            a2w2b, HMLP, nullptr, 0, a2b2, nullptr, chat, MEMD, MEMD, 3, 0);
            ps[np++] = mkgp(hcat + 1024, 3072, HMLP, nullptr, 0, 0,
                            g1w2b, HMLP, nullptr, 0, g1b2, nullptr, gm1, MEMD, MEMD, 2, 0);
            ps[np++] = mkgp(hcat + 2048, 3072, HMLP, nullptr, 0, 0,
                            g2w2b, HMLP, nullptr, 0, g2b2, nullptr, gm2, MEMD, MEMD, 2, 0);
            launch_group64(stream, ps, np);
        }
    }

    // epilogue
    mem_update<<<(NB * MEMD + 255) / 256, 256, 0, stream>>>(memb, membb, gm1, gm2, chat);
    {
        GP ps[1] = { mkgp(hsb[0], TOTH, TOTH, membb, MEMD, MEMD,
                          ow1b, 1536, ow1b + TOTH, 1536, ob1, nullptr,
                          hout, HMLP, HMLP, 1, 0) };
        launch_group64(stream, ps, 1);
    }
    out_dot<<<NB / 4, 256, 0, stream>>>(hout, ow2, ob2, out);
}

// Round 18
// 5254.597 us; speedup vs baseline: 1.0985x; 1.0985x over previous
//
#include <hip/hip_runtime.h>
#include <hip/hip_bf16.h>

typedef unsigned short u16;
typedef unsigned int   u32;
typedef __attribute__((ext_vector_type(8))) short s16x8;   // 8 bf16 = 4 VGPRs
typedef __attribute__((ext_vector_type(4))) float f32x4;

// ---- problem constants ----
#define NB   1024
#define TT   64
#define DXL  300
#define DXA  74
#define DXV  35
#define DX   (DXL+DXA+DXV)   // 409
#define DHL  512
#define DHA  256
#define DHV  256
#define TOTH 1024
#define MEMD 512
#define HMLP 1024
#define ATTIN 2048
#define GAMIN 2560
// padded x widths (multiples of 64)
#define PXL  320
#define PXA  128
#define PXV  64

__device__ __forceinline__ u16 f2b(float f) {
    union { float f; u32 u; } x; x.f = f;
    u32 r = x.u + 0x7fffu + ((x.u >> 16) & 1u);
    return (u16)(r >> 16);
}

__device__ __forceinline__ void gload_lds16(const void* g, void* l) {
    __builtin_amdgcn_global_load_lds(
        (const __attribute__((address_space(1))) unsigned int*)g,
        (__attribute__((address_space(3))) unsigned int*)l,
        16, 0, 0);
}

// ---------------------------------------------------------------------------
// Grouped bf16 MFMA NT GEMM — R10 configuration (best measured: 5255-5286 us,
// reproduced twice). 64x64 tile, BK=64, 256 threads = 4 waves (2x2), each
// wave 32x32 via 2x2 fragments of mfma_f32_16x16x32_bf16. Double-buffered
// LDS (32 KB -> 5 blocks/CU). BOTH A and B staged via global_load_lds with
// XOR chunk swizzle (source pre-swizzle + swizzled ds_read, rule #21).
// Grid is 1-D problem-major (blocks of one problem contiguous, bx fast),
// host orders problems by descending K -> shortest blocks dispatched last.
// Falsified levers (R11-R17): LDS-BW halving x2, barrier halving (BK=128),
// B-latency prefetch, no-LDS, XCD swizzle, 128^2 tile — all neutral/worse.
// C[m][n] = act(sum_k A[m][k]*W[n][k] + bias); A/W composite in k.
// All dims multiples of 64; M = 1024 (16 row-blocks per problem).
// ---------------------------------------------------------------------------
struct GP {
    const u16* A0; const u16* A1; const u16* W0; const u16* W1;
    const float* b0; const float* b1; void* C;
    int lda0, K0, lda1, K1, ldw0, ldw1, ldc, act, outbf, bStart, gx;
};

__global__ __launch_bounds__(256) void gemm_group(GP p0, GP p1, GP p2,
                                                  GP p3, GP p4, GP p5)
{
    __shared__ u16 As[2][64 * 64];
    __shared__ u16 Bs[2][64 * 64];
    GP p;
    {
        int bx = blockIdx.x;
        if      (bx >= p5.bStart) p = p5;
        else if (bx >= p4.bStart) p = p4;
        else if (bx >= p3.bStart) p = p3;
        else if (bx >= p2.bStart) p = p2;
        else if (bx >= p1.bStart) p = p1;
        else                      p = p0;
    }
    const int tid  = threadIdx.x;
    const int wid  = tid >> 6;
    const int lane = tid & 63;
    const int local = blockIdx.x - p.bStart;
    const int by  = local / p.gx;            // 0..15 (M row-block)
    const int bm  = by * 64;
    const int bn  = (local - by * p.gx) * 64;
    const int wr = wid >> 1, wc = wid & 1;
    const int nt = (p.K0 + p.K1) >> 6;
    const int e0 = wid * 2 * 64 + lane;

    auto stage = [&](int t, int buf) {
        int k0 = t << 6;
        const u16 *Ap, *Wp; int ldA, ldW, ka;
        if (k0 < p.K0) { Ap = p.A0; ldA = p.lda0; ka = k0;        Wp = p.W0; ldW = p.ldw0; }
        else           { Ap = p.A1; ldA = p.lda1; ka = k0 - p.K0; Wp = p.W1; ldW = p.ldw1; }
        #pragma unroll
        for (int i = 0; i < 2; ++i) {
            int e   = e0 + i * 64;
            int row = e >> 3;                 // 0..63
            int c   = (e & 7) ^ (row & 7);    // logical 16B chunk (inverse swizzle)
            gload_lds16(Ap + (size_t)(bm + row) * ldA + ka + c * 8,
                        (char*)&As[buf][0] + (wid * 2 + i) * 1024);
            gload_lds16(Wp + (size_t)(bn + row) * ldW + ka + c * 8,
                        (char*)&Bs[buf][0] + (wid * 2 + i) * 1024);
        }
    };

    f32x4 acc[2][2] = {};
    stage(0, 0);
    __syncthreads();

    for (int t = 0; t < nt; ++t) {
        if (t + 1 < nt) stage(t + 1, (t + 1) & 1);
        const char* Ab = (const char*)&As[t & 1][0];
        const char* Bb = (const char*)&Bs[t & 1][0];
        #pragma unroll
        for (int ks = 0; ks < 2; ++ks) {
            s16x8 af[2], bf[2];
            const int ca = ks * 4 + (lane >> 4);
            #pragma unroll
            for (int f = 0; f < 2; ++f) {
                int ra = wr * 32 + f * 16 + (lane & 15);
                af[f] = *(const s16x8*)(Ab + ra * 128 + ((ca ^ (ra & 7))) * 16);
                int rb = wc * 32 + f * 16 + (lane & 15);
                bf[f] = *(const s16x8*)(Bb + rb * 128 + ((ca ^ (rb & 7))) * 16);
            }
            #pragma unroll
            for (int fi = 0; fi < 2; ++fi)
                #pragma unroll
                for (int fj = 0; fj < 2; ++fj)
                    acc[fi][fj] = __builtin_amdgcn_mfma_f32_16x16x32_bf16(
                        af[fi], bf[fj], acc[fi][fj], 0, 0, 0);
        }
        __syncthreads();
    }

    // epilogue: C/D layout col = lane&15, row = (lane>>4)*4 + reg  [m89-verified]
    #pragma unroll
    for (int fi = 0; fi < 2; ++fi)
        #pragma unroll
        for (int fj = 0; fj < 2; ++fj) {
            int col = bn + wc * 32 + fj * 16 + (lane & 15);
            float bia = p.b0[col];
            if (p.b1) bia += p.b1[col];
            #pragma unroll
            for (int r4 = 0; r4 < 4; ++r4) {
                int row = bm + wr * 32 + fi * 16 + (lane >> 4) * 4 + r4;
                float v = acc[fi][fj][r4] + bia;
                if (p.act == 1)      v = fmaxf(v, 0.f);
                else if (p.act == 2) v = 1.f / (1.f + __expf(-v));
                else if (p.act == 3) v = tanhf(v);
                if (p.outbf) ((u16*)p.C)[(size_t)row * p.ldc + col] = f2b(v);
                else         ((float*)p.C)[(size_t)row * p.ldc + col] = v;
            }
        }
}

// ---------------------------------------------------------------------------
// pointwise device helpers
// ---------------------------------------------------------------------------
__device__ __forceinline__ void lstm_elem(
    const float* __restrict__ gl, const float* __restrict__ ga,
    const float* __restrict__ gv, const float* __restrict__ cs_prev,
    float* __restrict__ cs_new, u16* __restrict__ cs_new_b,
    u16* __restrict__ hs_new_b, int idx)
{
    int n = idx >> 10, u = idx & 1023;
    const float* g; int dh, gu;
    if (u < DHL)            { g = gl; dh = DHL; gu = u; }
    else if (u < DHL + DHA) { g = ga; dh = DHA; gu = u - DHL; }
    else                    { g = gv; dh = DHV; gu = u - DHL - DHA; }
    const float* grow = g + (size_t)n * 4 * dh;
    float gi = grow[gu], gf = grow[dh + gu], gg = grow[2 * dh + gu], go = grow[3 * dh + gu];
    float c  = cs_prev[idx];
    float si = 1.f / (1.f + __expf(-gi));
    float sf = 1.f / (1.f + __expf(-gf));
    float so = 1.f / (1.f + __expf(-go));
    float c2 = sf * c + si * tanhf(gg);
    float h2 = so * tanhf(c2);
    cs_new[idx]   = c2;
    cs_new_b[idx] = f2b(c2);
    hs_new_b[idx] = f2b(h2);
}

__device__ __forceinline__ void xcvt_elem(
    const float* __restrict__ X, int t, int n, int u,
    u16* __restrict__ xl, u16* __restrict__ xa, u16* __restrict__ xv)
{
    const float* row = X + ((size_t)t * NB + n) * DX;
    if (u < PXL)            xl[n * PXL + u] = f2b(u < DXL ? row[u] : 0.f);
    else if (u < PXL + PXA) { int q = u - PXL;       xa[n * PXA + q] = f2b(q < DXA ? row[DXL + q] : 0.f); }
    else                    { int q = u - PXL - PXA; xv[n * PXV + q] = f2b(q < DXV ? row[DXL + DXA + q] : 0.f); }
}

// standalone LSTM pointwise (prologue step 0) + x(1) conversion
__global__ void lstm_pointwise(const float* __restrict__ gl,
                               const float* __restrict__ ga,
                               const float* __restrict__ gv,
                               const float* __restrict__ cs_prev,
                               float* __restrict__ cs_new,
                               u16* __restrict__ cs_new_b,
                               u16* __restrict__ hs_new_b,
                               const float* __restrict__ X, int tnext,
                               u16* __restrict__ xl, u16* __restrict__ xa,
                               u16* __restrict__ xv)
{
    int idx = blockIdx.x * blockDim.x + threadIdx.x;
    if (idx >= NB * TOTH) return;
    lstm_elem(gl, ga, gv, cs_prev, cs_new, cs_new_b, hs_new_b, idx);
    int n = idx >> 10, u = idx & 1023;
    if (tnext < TT && u < 512) xcvt_elem(X, tnext, n, u, xl, xa, xv);
}

// ---------------------------------------------------------------------------
// fused mid kernel: mem-update(t-1) + softmax/attend(t) + LSTM pointwise(t+1)
// + x(t+2) conversion. One block (256 thr) per batch row.  [validated R6-R17]
// ---------------------------------------------------------------------------
__global__ __launch_bounds__(256) void fused_mid(
    const float* __restrict__ logits,
    const float* __restrict__ csP,          // c(t)  fp32
    const float* __restrict__ csN,          // c(t+1) fp32
    u16* __restrict__ attended_b,
    int do_mem,
    float* __restrict__ memb, u16* __restrict__ membb,
    const float* __restrict__ g1, const float* __restrict__ g2,
    const float* __restrict__ chat,
    int do_pw,
    const float* __restrict__ gl, const float* __restrict__ ga,
    const float* __restrict__ gv,
    float* __restrict__ pw_cs_new,          // csf[t&1] (c(t+2))
    u16* __restrict__ pw_cs_new_b,
    u16* __restrict__ pw_hs_new_b,
    const float* __restrict__ X, int tnext, // t+2
    u16* __restrict__ xl, u16* __restrict__ xa, u16* __restrict__ xv)
{
    int n = blockIdx.x;
    int tid = threadIdx.x, lane = tid & 63, wid = tid >> 6;

    if (do_mem) {
        for (int k = tid; k < MEMD; k += 256) {
            size_t i = (size_t)n * MEMD + k;
            float v = g1[i] * memb[i] + g2[i] * chat[i];
            memb[i]  = v;
            membb[i] = f2b(v);
        }
    }

    const float* z = logits + (size_t)n * ATTIN;
    __shared__ float sred[4];

    float m = -1e30f;
    for (int k = tid; k < ATTIN; k += 256) m = fmaxf(m, z[k]);
    #pragma unroll
    for (int off = 1; off < 64; off <<= 1) m = fmaxf(m, __shfl_xor(m, off));
    if (lane == 0) sred[wid] = m;
    __syncthreads();
    m = fmaxf(fmaxf(sred[0], sred[1]), fmaxf(sred[2], sred[3]));
    __syncthreads();

    float s = 0.f;
    for (int k = tid; k < ATTIN; k += 256) s += __expf(z[k] - m);
    #pragma unroll
    for (int off = 1; off < 64; off <<= 1) s += __shfl_xor(s, off);
    if (lane == 0) sred[wid] = s;
    __syncthreads();
    s = sred[0] + sred[1] + sred[2] + sred[3];
    float inv = 1.f / s;

    for (int k = tid; k < ATTIN; k += 256) {
        float cs = (k < TOTH) ? csP[(size_t)n * TOTH + k]
                              : csN[(size_t)n * TOTH + (k - TOTH)];
        attended_b[(size_t)n * ATTIN + k] = f2b(__expf(z[k] - m) * inv * cs);
    }

    if (do_pw) {
        __syncthreads();   // all attend-reads of csP row n done before overwrite
        #pragma unroll
        for (int j = 0; j < 4; ++j) {
            int u = tid + j * 256;
            lstm_elem(gl, ga, gv, csN, pw_cs_new, pw_cs_new_b, pw_hs_new_b,
                      n * 1024 + u);
        }
        if (tnext < TT) {
            #pragma unroll
            for (int j = 0; j < 2; ++j) {
                int u = tid + j * 256;
                xcvt_elem(X, tnext, n, u, xl, xa, xv);
            }
        }
    }
}

__global__ void mem_update(float* __restrict__ memb,
                           u16* __restrict__ memb_b,
                           const float* __restrict__ g1,
                           const float* __restrict__ g2,
                           const float* __restrict__ chat)
{
    int idx = blockIdx.x * blockDim.x + threadIdx.x;
    if (idx >= NB * MEMD) return;
    float v = g1[idx] * memb[idx] + g2[idx] * chat[idx];
    memb[idx]   = v;
    memb_b[idx] = f2b(v);
}

__global__ __launch_bounds__(256) void out_dot(const float* __restrict__ hid,
                                               const float* __restrict__ w2,
                                               const float* __restrict__ b2,
                                               float* __restrict__ out)
{
    int wid = threadIdx.x >> 6, lane = threadIdx.x & 63;
    int n = blockIdx.x * 4 + wid;
    if (n >= NB) return;
    const float* h = hid + (size_t)n * HMLP;
    float s = 0.f;
    for (int k = lane; k < HMLP; k += 64) s += h[k] * w2[k];
    #pragma unroll
    for (int off = 1; off < 64; off <<= 1) s += __shfl_xor(s, off);
    if (lane == 0) out[n] = s + b2[0];
}

// initial x conversion (t=0)
__global__ void cvt_x(const float* __restrict__ X,
                      u16* __restrict__ xl, u16* __restrict__ xa, u16* __restrict__ xv,
                      int t)
{
    int idx = blockIdx.x * blockDim.x + threadIdx.x;   // NB * 512
    if (idx >= NB * 512) return;
    xcvt_elem(X, t, idx >> 9, idx & 511, xl, xa, xv);
}

// bias concat for g12 L1 GEMM: [g1b1 | g2b1]
__global__ void concat2(const float* __restrict__ a, const float* __restrict__ b,
                        float* __restrict__ d)
{
    int i = blockIdx.x * 256 + threadIdx.x;
    if (i < 1024)      d[i] = a[i];
    else if (i < 2048) d[i] = b[i - 1024];
}

// grouped weight conversion: fp32->bf16 (optionally k-padded)
#define NWC 15
struct WDesc { const float* src; u16* dst; int rows, ksrc, kdst, bstart; };
struct WPack { WDesc d[NWC]; };

__global__ __launch_bounds__(256) void wcvt_all(WPack wp)
{
    int bx = blockIdx.x;
    int di = 0;
    #pragma unroll
    for (int i = 1; i < NWC; ++i) if (bx >= wp.d[i].bstart) di = i;
    WDesc d = wp.d[di];
    int n = d.rows * d.kdst;
    int base = (bx - d.bstart) * 2048 + threadIdx.x;
    if (d.ksrc == d.kdst) {
        #pragma unroll
        for (int j = 0; j < 8; ++j) {
            int idx = base + j * 256;
            if (idx < n) d.dst[idx] = f2b(d.src[idx]);
        }
    } else {
        #pragma unroll
        for (int j = 0; j < 8; ++j) {
            int idx = base + j * 256;
            if (idx < n) {
                int r = idx / d.kdst, c = idx - r * d.kdst;
                d.dst[idx] = f2b(c < d.ksrc ? d.src[(size_t)r * d.ksrc + c] : 0.f);
            }
        }
    }
}

__global__ void fill0(u32* __restrict__ p, int n)
{
    int i = blockIdx.x * blockDim.x + threadIdx.x;
    if (i < n) p[i] = 0u;
}

// ---------------------------------------------------------------------------
// host side
// ---------------------------------------------------------------------------
static GP mkgp(const u16* A0, int lda0, int K0, const u16* A1, int lda1, int K1,
               const u16* W0, int ldw0, const u16* W1, int ldw1,
               const float* b0, const float* b1, void* C, int ldc,
               int Nout, int act, int outbf)
{
    GP p;
    p.A0 = A0; p.A1 = A1; p.W0 = W0; p.W1 = W1; p.b0 = b0; p.b1 = b1; p.C = C;
    p.lda0 = lda0; p.K0 = K0; p.lda1 = lda1; p.K1 = K1;
    p.ldw0 = ldw0; p.ldw1 = ldw1; p.ldc = ldc; p.act = act; p.outbf = outbf;
    p.bStart = 0; p.gx = Nout / 64;
    return p;
}

// 1-D problem-major launch; caller orders problems descending-K (short tail).
static void launch_group(hipStream_t s, GP* p, int np)
{
    int total = 0;
    for (int i = 0; i < np; ++i) { p[i].bStart = total; total += p[i].gx * 16; }
    GP dummy = {};
    dummy.bStart = 0x7fffffff;
    GP a1 = (np > 1) ? p[1] : dummy;
    GP a2 = (np > 2) ? p[2] : dummy;
    GP a3 = (np > 3) ? p[3] : dummy;
    GP a4 = (np > 4) ? p[4] : dummy;
    GP a5 = (np > 5) ? p[5] : dummy;
    gemm_group<<<dim3(total), 256, 0, s>>>(p[0], a1, a2, a3, a4, a5);
}

extern "C" void kernel_launch(void* const* d_in, const int* in_sizes, int n_in,
                              void* d_out, int out_size, void* d_ws, size_t ws_size,
                              hipStream_t stream)
{
    const float* X     = (const float*)d_in[0];
    const float* Wih_l = (const float*)d_in[5];
    const float* Whh_l = (const float*)d_in[6];
    const float* bih_l = (const float*)d_in[7];
    const float* bhh_l = (const float*)d_in[8];
    const float* Wih_a = (const float*)d_in[9];
    const float* Whh_a = (const float*)d_in[10];
    const float* bih_a = (const float*)d_in[11];
    const float* bhh_a = (const float*)d_in[12];
    const float* Wih_v = (const float*)d_in[13];
    const float* Whh_v = (const float*)d_in[14];
    const float* bih_v = (const float*)d_in[15];
    const float* bhh_v = (const float*)d_in[16];
    const float* a1w1  = (const float*)d_in[17];
    const float* a1b1  = (const float*)d_in[18];
    const float* a1w2  = (const float*)d_in[19];
    const float* a1b2  = (const float*)d_in[20];
    const float* a2w1  = (const float*)d_in[21];
    const float* a2b1  = (const float*)d_in[22];
    const float* a2w2  = (const float*)d_in[23];
    const float* a2b2  = (const float*)d_in[24];
    const float* g1w1  = (const float*)d_in[25];
    const float* g1b1  = (const float*)d_in[26];
    const float* g1w2  = (const float*)d_in[27];
    const float* g1b2  = (const float*)d_in[28];
    const float* g2w1  = (const float*)d_in[29];
    const float* g2b1  = (const float*)d_in[30];
    const float* g2w2  = (const float*)d_in[31];
    const float* g2b2  = (const float*)d_in[32];
    const float* ow1   = (const float*)d_in[33];
    const float* ob1   = (const float*)d_in[34];
    const float* ow2   = (const float*)d_in[35];
    const float* ob2   = (const float*)d_in[36];
    float* out = (float*)d_out;

    // ---- workspace carve (256B aligned) ----
    char* wsp = (char*)d_ws;
    auto take = [&](size_t bytes) -> char* {
        char* r = wsp; wsp += (bytes + 255) & ~(size_t)255; return r;
    };
    float* cs0  = (float*)take((size_t)NB * TOTH * 4);
    float* cs1  = (float*)take((size_t)NB * TOTH * 4);
    float* memb = (float*)take((size_t)NB * MEMD * 4);
    float* gl   = (float*)take((size_t)NB * 2048 * 4);
    float* ga   = (float*)take((size_t)NB * 1024 * 4);
    float* gv   = (float*)take((size_t)NB * 1024 * 4);
    float* lgts = (float*)take((size_t)NB * ATTIN * 4);   // dedicated (round-4 lesson)
    float* chat = (float*)take((size_t)NB * MEMD * 4);
    float* gm1  = (float*)take((size_t)NB * MEMD * 4);
    float* gm2  = (float*)take((size_t)NB * MEMD * 4);
    float* hout = (float*)take((size_t)NB * HMLP * 4);
    float* cb2  = (float*)take((size_t)2048 * 4);
    u16* hs0b  = (u16*)take((size_t)NB * TOTH * 2);
    u16* hs1b  = (u16*)take((size_t)NB * TOTH * 2);
    u16* cs0b  = (u16*)take((size_t)NB * TOTH * 2);
    u16* cs1b  = (u16*)take((size_t)NB * TOTH * 2);
    u16* membb = (u16*)take((size_t)NB * MEMD * 2);
    u16* xlb   = (u16*)take((size_t)NB * PXL * 2);
    u16* xab   = (u16*)take((size_t)NB * PXA * 2);
    u16* xvb   = (u16*)take((size_t)NB * PXV * 2);
    u16* hid1b = (u16*)take((size_t)NB * HMLP * 2);
    u16* hcat  = (u16*)take((size_t)NB * 3072 * 2);        // [hid2|hg1|hg2]
    u16* attdb = (u16*)take((size_t)NB * ATTIN * 2);
    u16* wihlb = (u16*)take((size_t)2048 * PXL * 2);
    u16* whhlb = (u16*)take((size_t)2048 * DHL * 2);
    u16* wihab = (u16*)take((size_t)1024 * PXA * 2);
    u16* whhab = (u16*)take((size_t)1024 * DHA * 2);
    u16* wihvb = (u16*)take((size_t)1024 * PXV * 2);
    u16* whhvb = (u16*)take((size_t)1024 * DHV * 2);
    u16* a1w1b = (u16*)take((size_t)HMLP * ATTIN * 2);
    u16* a1w2b = (u16*)take((size_t)ATTIN * HMLP * 2);
    u16* a2w1b = (u16*)take((size_t)HMLP * ATTIN * 2);
    u16* g12w1b= (u16*)take((size_t)2048 * GAMIN * 2);     // [g1w1; g2w1]
    u16* a2w2b = (u16*)take((size_t)MEMD * HMLP * 2);
    u16* g1w2b = (u16*)take((size_t)MEMD * HMLP * 2);
    u16* g2w2b = (u16*)take((size_t)MEMD * HMLP * 2);
    u16* ow1b  = (u16*)take((size_t)HMLP * 1536 * 2);

    // ---- prologue: zero state, weight conversion, bias concat, x(0) ----
    {
        int nf = NB * (TOTH * 2 + MEMD);
        fill0<<<(nf + 255) / 256, 256, 0, stream>>>((u32*)cs0, nf);
        int nb = NB * (TOTH * 4 + MEMD) / 2;
        fill0<<<(nb + 255) / 256, 256, 0, stream>>>((u32*)hs0b, nb);
    }
    {
        WPack wp;
        const float* src[NWC] = { Wih_l, Whh_l, Wih_a, Whh_a, Wih_v, Whh_v,
                                  a1w1, a1w2, a2w1, g1w1, g2w1,
                                  a2w2, g1w2, g2w2, ow1 };
        u16* dst[NWC] = { wihlb, whhlb, wihab, whhab, wihvb, whhvb,
                          a1w1b, a1w2b, a2w1b, g12w1b, g12w1b + (size_t)1024 * GAMIN,
                          a2w2b, g1w2b, g2w2b, ow1b };
        int rows[NWC] = { 2048, 2048, 1024, 1024, 1024, 1024,
                          HMLP, ATTIN, HMLP, 1024, 1024,
                          MEMD, MEMD, MEMD, HMLP };
        int ksrc[NWC] = { DXL, DHL, DXA, DHA, DXV, DHV,
                          ATTIN, HMLP, ATTIN, GAMIN, GAMIN,
                          HMLP, HMLP, HMLP, 1536 };
        int kdst[NWC] = { PXL, DHL, PXA, DHA, PXV, DHV,
                          ATTIN, HMLP, ATTIN, GAMIN, GAMIN,
                          HMLP, HMLP, HMLP, 1536 };
        int total = 0;
        for (int i = 0; i < NWC; ++i) {
            wp.d[i].src = src[i]; wp.d[i].dst = dst[i];
            wp.d[i].rows = rows[i]; wp.d[i].ksrc = ksrc[i]; wp.d[i].kdst = kdst[i];
            wp.d[i].bstart = total;
            total += (rows[i] * kdst[i] + 2047) / 2048;
        }
        wcvt_all<<<total, 256, 0, stream>>>(wp);
    }
    concat2<<<8, 256, 0, stream>>>(g1b1, g2b1, cb2);
    cvt_x<<<(NB * 512 + 255) / 256, 256, 0, stream>>>(X, xlb, xab, xvb, 0);

    float* csf[2] = { cs0, cs1 };
    u16*   csb[2] = { cs0b, cs1b };
    u16*   hsb[2] = { hs0b, hs1b };

    // prologue: lstm gemms(0), pointwise(0), {att1L1(0)+lstm(1)}, att1L2(0)
    {
        GP ps[3] = {
            mkgp(xlb, PXL, PXL, hsb[0], TOTH, DHL,
                 wihlb, PXL, whhlb, DHL, bih_l, bhh_l, gl, 2048, 2048, 0, 0),
            mkgp(xab, PXA, PXA, hsb[0] + DHL, TOTH, DHA,
                 wihab, PXA, whhab, DHA, bih_a, bhh_a, ga, 1024, 1024, 0, 0),
            mkgp(xvb, PXV, PXV, hsb[0] + DHL + DHA, TOTH, DHV,
                 wihvb, PXV, whhvb, DHV, bih_v, bhh_v, gv, 1024, 1024, 0, 0) };
        launch_group(stream, ps, 3);
    }
    lstm_pointwise<<<(NB * TOTH + 255) / 256, 256, 0, stream>>>(
        gl, ga, gv, csf[0], csf[1], csb[1], hsb[1], X, 1, xlb, xab, xvb);
    {
        GP ps[4] = {
            mkgp(csb[0], TOTH, TOTH, csb[1], TOTH, TOTH,
                 a1w1b, ATTIN, a1w1b + TOTH, ATTIN, a1b1, nullptr,
                 hid1b, HMLP, HMLP, 1, 1),
            mkgp(xlb, PXL, PXL, hsb[1], TOTH, DHL,
                 wihlb, PXL, whhlb, DHL, bih_l, bhh_l, gl, 2048, 2048, 0, 0),
            mkgp(xab, PXA, PXA, hsb[1] + DHL, TOTH, DHA,
                 wihab, PXA, whhab, DHA, bih_a, bhh_a, ga, 1024, 1024, 0, 0),
            mkgp(xvb, PXV, PXV, hsb[1] + DHL + DHA, TOTH, DHV,
                 wihvb, PXV, whhvb, DHV, bih_v, bhh_v, gv, 1024, 1024, 0, 0) };
        launch_group(stream, ps, 4);
    }
    {
        GP ps[1] = { mkgp(hid1b, HMLP, HMLP, nullptr, 0, 0,
                          a1w2b, HMLP, nullptr, 0, a1b2, nullptr,
                          lgts, ATTIN, ATTIN, 0, 0) };
        launch_group(stream, ps, 1);
    }

    // main loop: 3 launches/step
    for (int t = 0; t < TT; ++t) {
        // 1) fused_mid(t): mem(t-1) + softmax/attend(t) + pointwise(t+1) + x(t+2)
        fused_mid<<<NB, 256, 0, stream>>>(
            lgts, csf[t & 1], csf[(t + 1) & 1], attdb,
            t > 0 ? 1 : 0, memb, membb, gm1, gm2, chat,
            t < TT - 1 ? 1 : 0, gl, ga, gv,
            csf[t & 1], csb[t & 1], hsb[t & 1],
            X, t + 2, xlb, xab, xvb);

        // 2) G1 (problem-major, descending K -> short tail)
        {
            GP ps[6]; int np = 0;
            ps[np++] = mkgp(attdb, ATTIN, ATTIN, membb, MEMD, MEMD,
                            g12w1b, GAMIN, g12w1b + ATTIN, GAMIN, cb2, nullptr,
                            hcat + 1024, 3072, 2048, 1, 1);
            ps[np++] = mkgp(attdb, ATTIN, ATTIN, nullptr, 0, 0,
                            a2w1b, ATTIN, nullptr, 0, a2b1, nullptr,
                            hcat, 3072, 1024, 1, 1);
            if (t < TT - 1)
                ps[np++] = mkgp(csb[(t + 1) & 1], TOTH, TOTH, csb[t & 1], TOTH, TOTH,
                                a1w1b, ATTIN, a1w1b + TOTH, ATTIN, a1b1, nullptr,
                                hid1b, HMLP, HMLP, 1, 1);
            if (t < TT - 2) {
                ps[np++] = mkgp(xlb, PXL, PXL, hsb[t & 1], TOTH, DHL,
                                wihlb, PXL, whhlb, DHL, bih_l, bhh_l, gl, 2048, 2048, 0, 0);
                ps[np++] = mkgp(xab, PXA, PXA, hsb[t & 1] + DHL, TOTH, DHA,
                                wihab, PXA, whhab, DHA, bih_a, bhh_a, ga, 1024, 1024, 0, 0);
                ps[np++] = mkgp(xvb, PXV, PXV, hsb[t & 1] + DHL + DHA, TOTH, DHV,
                                wihvb, PXV, whhvb, DHV, bih_v, bhh_v, gv, 1024, 1024, 0, 0);
            }
            launch_group(stream, ps, np);
        }

        // 3) G2: [att1-L2(t+1) if t<63] + att2-L2(t), g1-L2(t), g2-L2(t)
        {
            GP ps[4]; int np = 0;
            if (t < TT - 1)
                ps[np++] = mkgp(hid1b, HMLP, HMLP, nullptr, 0, 0,
                                a1w2b, HMLP, nullptr, 0, a1b2, nullptr,
                                lgts, ATTIN, ATTIN, 0, 0);
            ps[np++] = mkgp(hcat, 3072, HMLP, nullptr, 0, 0,
                            a2w2b, HMLP, nullptr, 0, a2b2, nullptr, chat, MEMD, MEMD, 3, 0);
            ps[np++] = mkgp(hcat + 1024, 3072, HMLP, nullptr, 0, 0,
                            g1w2b, HMLP, nullptr, 0, g1b2, nullptr, gm1, MEMD, MEMD, 2, 0);
            ps[np++] = mkgp(hcat + 2048, 3072, HMLP, nullptr, 0, 0,
                            g2w2b, HMLP, nullptr, 0, g2b2, nullptr, gm2, MEMD, MEMD, 2, 0);
            launch_group(stream, ps, np);
        }
    }

    // epilogue: final mem update (step 63), output MLP
    mem_update<<<(NB * MEMD + 255) / 256, 256, 0, stream>>>(memb, membb, gm1, gm2, chat);
    {
        GP ps[1] = { mkgp(hsb[0], TOTH, TOTH, membb, MEMD, MEMD,
                          ow1b, 1536, ow1b + TOTH, 1536, ob1, nullptr,
                          hout, HMLP, HMLP, 1, 0) };
        launch_group(stream, ps, 1);
    }
    out_dot<<<NB / 4, 256, 0, stream>>>(hout, ow2, ob2, out);
}